// Round 2
// baseline (273.057 us; speedup 1.0000x reference)
//
#include <hip/hip_runtime.h>

// TemporalMultipyPool3D: x (8,512,16,28,28) f32 -> out (8,512,7,1,1) f32
// All three branches derive from the 4x4x4 grid of window maxes m4[it][jw][kh]
// over windows (4,7,7):
//   out[0]   = max over all 64
//   out[1:3] = quarter-sums of 2x2x2 block-maxes (n=2 windows are exact unions)
//   out[3:7] = sixteenth-sums over (jw,kh)           (n=4 windows directly)
// L = Ty//n = 1 for every branch, so the "temporal product" is the identity
// and Ty == n means no padding — verified exact (R0 first launch absmax 0.0).
//
// R1: atomic-free deterministic reduction. R0 used LDS atomicMax (int-key
// trick) and diverged across graph replays; all shared-address writes are
// now replaced by private-slot writes + barrier + owner-reduce.

#define T_DIM 16
#define W_DIM 28
#define H_DIM 28
#define SLICE (T_DIM * W_DIM * H_DIM)  // 12544 floats per (b,c)
#define ROWS  (T_DIM * W_DIM)          // 448 H-rows per slice

__global__ __launch_bounds__(256) void tmpool_kernel(const float* __restrict__ x,
                                                     float* __restrict__ out) {
    // Phase-1 scratch: per-row kh-bin maxes, private slot per row (no races).
    __shared__ __align__(16) float rowmax[ROWS * 4];  // 7168 B
    __shared__ float m4[64];                          // window maxes it*16+jw*4+kh

    const int tid = threadIdx.x;
    const int bc  = blockIdx.x;

    const float4* base = (const float4*)(x + (size_t)bc * SLICE);

    // Phase 1: each thread handles whole H-rows (28 floats = 7 float4s).
    // Rows are contiguous in memory, so a wave's 64 rows cover a contiguous
    // 7 KiB span — every cache line fully consumed within the wave.
    for (int r = tid; r < ROWS; r += 256) {
        const float4* rp = base + r * 7;
        float4 v0 = rp[0], v1 = rp[1], v2 = rp[2], v3 = rp[3];
        float4 v4 = rp[4], v5 = rp[5], v6 = rp[6];
        // kh bins: h in [0,7) [7,14) [14,21) [21,28)
        float m0 = fmaxf(fmaxf(fmaxf(v0.x, v0.y), fmaxf(v0.z, v0.w)),
                         fmaxf(fmaxf(v1.x, v1.y), v1.z));
        float m1 = fmaxf(fmaxf(fmaxf(v1.w, v2.x), fmaxf(v2.y, v2.z)),
                         fmaxf(fmaxf(v2.w, v3.x), v3.y));
        float m2 = fmaxf(fmaxf(fmaxf(v3.z, v3.w), fmaxf(v4.x, v4.y)),
                         fmaxf(fmaxf(v4.z, v4.w), v5.x));
        float m3 = fmaxf(fmaxf(fmaxf(v5.y, v5.z), fmaxf(v5.w, v6.x)),
                         fmaxf(fmaxf(v6.y, v6.z), v6.w));
        *(float4*)&rowmax[r * 4] = make_float4(m0, m1, m2, m3);
    }
    __syncthreads();

    // Phase 2: 64 threads each own one (it,jw,kh) bin; reduce its 28 rows.
    if (tid < 64) {
        const int it = tid >> 4;
        const int jw = (tid >> 2) & 3;
        const int kh = tid & 3;
        float m = -INFINITY;
        #pragma unroll
        for (int dt = 0; dt < 4; dt++) {
            const int rbase = ((4 * it + dt) * 28 + 7 * jw) * 4 + kh;
            #pragma unroll
            for (int dw = 0; dw < 7; dw++)
                m = fmaxf(m, rowmax[rbase + dw * 4]);
        }
        m4[tid] = m;
    }
    __syncthreads();

    // Phase 3: 7 outputs per (b,c).
    if (tid < 7) {
        float* o = out + (size_t)bc * 7;
        if (tid == 0) {
            float m = -INFINITY;
            #pragma unroll
            for (int i = 0; i < 64; i++) m = fmaxf(m, m4[i]);
            o[0] = m;
        } else if (tid < 3) {
            const int i2 = tid - 1;
            float s = 0.f;
            #pragma unroll
            for (int j2 = 0; j2 < 2; j2++)
                #pragma unroll
                for (int k2 = 0; k2 < 2; k2++) {
                    float m = -INFINITY;
                    #pragma unroll
                    for (int di = 0; di < 2; di++)
                        #pragma unroll
                        for (int dj = 0; dj < 2; dj++)
                            #pragma unroll
                            for (int dk = 0; dk < 2; dk++)
                                m = fmaxf(m, m4[(2 * i2 + di) * 16 +
                                                (2 * j2 + dj) * 4 + (2 * k2 + dk)]);
                    s += m;
                }
            o[1 + i2] = s * 0.25f;
        } else {
            const int i = tid - 3;
            float s = 0.f;
            #pragma unroll
            for (int jk = 0; jk < 16; jk++) s += m4[i * 16 + jk];
            o[3 + i] = s * (1.0f / 16.0f);
        }
    }
}

extern "C" void kernel_launch(void* const* d_in, const int* in_sizes, int n_in,
                              void* d_out, int out_size, void* d_ws, size_t ws_size,
                              hipStream_t stream) {
    const float* x = (const float*)d_in[0];
    float* out = (float*)d_out;
    // 8*512 = 4096 (b,c) slices, one block each
    tmpool_kernel<<<4096, 256, 0, stream>>>(x, out);
}